// Round 4
// baseline (475.566 us; speedup 1.0000x reference)
//
#include <hip/hip_runtime.h>
#include <hip/hip_bf16.h>

// RGCN layer: out = relu(x @ W_self^T + b + agg/deg)
// Pipeline:
//   0. prep: xb = bf16(x), Bt = bf16([W_rel; W_self^T])  [128 out][1152 k]
//   1. counting-sort edges by key = dst*8+rel (hist -> scan -> reorder src)
//   2. fused aggregate+GEMM: per 64-node tile, gather bin sums directly into
//      a 64KB swizzled LDS A-tile (3 K-phases: rels 0-3, rels 4-7, self),
//      MFMA from LDS with B-frags straight from global (L2-hot), fp32 acc
//      persists across phases. A-matrix never materialized in global.

#define D 128
#define RNUM 8
#define KREL 1024
#define KTOT 1152
#define BLK_M 64
#define PHK 512              // K columns per rel-phase (4 rels x 128)

typedef short short8 __attribute__((ext_vector_type(8)));
typedef float float4v __attribute__((ext_vector_type(4)));

// fp32 -> bf16 round-nearest-even (bit pattern)
static __device__ __forceinline__ unsigned int f2b(float f) {
    unsigned int u = __float_as_uint(f);
    return (u + 0x7fffu + ((u >> 16) & 1u)) >> 16;
}
static __device__ __forceinline__ float b2f_lo(unsigned int u) {
    return __uint_as_float(u << 16);
}
static __device__ __forceinline__ float b2f_hi(unsigned int u) {
    return __uint_as_float(u & 0xffff0000u);
}

// ---------- prep: xb = bf16(x); Bt = bf16 [128 out][1152 k] ----------
__global__ void prep_kernel(const float* __restrict__ x,
                            const float* __restrict__ W_rel,
                            const float* __restrict__ W_self,
                            unsigned short* __restrict__ xb,
                            unsigned short* __restrict__ Bt,
                            int Nn, int xb_blocks) {
    if (blockIdx.x < (unsigned)xb_blocks) {
        int t = blockIdx.x * 256 + threadIdx.x;
        int n = t >> 5;              // 32 threads/row, 4 cols each
        int c = (t & 31) * 4;
        if (n >= Nn) return;
        float4 v = *(const float4*)(x + (size_t)n * D + c);
        unsigned int p0 = f2b(v.x) | (f2b(v.y) << 16);
        unsigned int p1 = f2b(v.z) | (f2b(v.w) << 16);
        *(uint2*)(xb + (size_t)n * D + c) = make_uint2(p0, p1);
    } else {
        int idx = (blockIdx.x - xb_blocks) * 256 + threadIdx.x;
        if (idx >= 128 * KTOT) return;
        int o = idx / KTOT;
        int k = idx - o * KTOT;
        float v = (k < KREL) ? W_rel[(size_t)k * D + o]   // [r][d][o] flat = k*128+o
                             : W_self[(size_t)o * D + (k - KREL)];
        Bt[idx] = (unsigned short)f2b(v);
    }
}

// ---------- counting sort ----------
__global__ void hist_kernel(const int* __restrict__ ei, const int* __restrict__ et,
                            int* __restrict__ hist, int E) {
    int e = blockIdx.x * 256 + threadIdx.x;
    if (e >= E) return;
    int key = ei[E + e] * RNUM + et[e];
    atomicAdd(hist + key, 1);
}

__global__ void scan1_kernel(const int* __restrict__ hist, int* __restrict__ bsum, int nb) {
    __shared__ int red[256];
    int t = threadIdx.x;
    int base = blockIdx.x * 1024 + t * 4;
    int s = 0;
#pragma unroll
    for (int i = 0; i < 4; ++i) if (base + i < nb) s += hist[base + i];
    red[t] = s;
    __syncthreads();
    for (int off = 128; off > 0; off >>= 1) {
        if (t < off) red[t] += red[t + off];
        __syncthreads();
    }
    if (t == 0) bsum[blockIdx.x] = red[0];
}

__global__ void scan2_kernel(int* __restrict__ bsum, int nparts) {
    __shared__ int tmp[1024];
    int t = threadIdx.x;
    tmp[t] = (t < nparts) ? bsum[t] : 0;
    __syncthreads();
    for (int off = 1; off < 1024; off <<= 1) {
        int v = (t >= off) ? tmp[t - off] : 0;
        __syncthreads();
        tmp[t] += v;
        __syncthreads();
    }
    if (t < nparts) bsum[t] = (t == 0) ? 0 : tmp[t - 1];   // exclusive
}

__global__ void scan3_kernel(const int* __restrict__ hist, const int* __restrict__ bsum,
                             int* __restrict__ offsets, int* __restrict__ cursor,
                             int nb, int E) {
    __shared__ int red[256];
    int t = threadIdx.x;
    int base = blockIdx.x * 1024 + t * 4;
    int v[4]; int s = 0;
#pragma unroll
    for (int i = 0; i < 4; ++i) { v[i] = (base + i < nb) ? hist[base + i] : 0; s += v[i]; }
    red[t] = s;
    __syncthreads();
    for (int off = 1; off < 256; off <<= 1) {       // Hillis-Steele inclusive
        int u = (t >= off) ? red[t - off] : 0;
        __syncthreads();
        red[t] += u;
        __syncthreads();
    }
    int p = bsum[blockIdx.x] + red[t] - s;          // exclusive prefix for this thread
#pragma unroll
    for (int i = 0; i < 4; ++i) {
        if (base + i < nb) { offsets[base + i] = p; cursor[base + i] = p; }
        p += v[i];
    }
    if (blockIdx.x == 0 && t == 0) offsets[nb] = E;  // sentinel
}

__global__ void reorder_kernel(const int* __restrict__ ei, const int* __restrict__ et,
                               int* __restrict__ cursor, int* __restrict__ sorted_src, int E) {
    int e = blockIdx.x * 256 + threadIdx.x;
    if (e >= E) return;
    int key = ei[E + e] * RNUM + et[e];
    int pos = atomicAdd(cursor + key, 1);
    sorted_src[pos] = ei[e];
}

// ---------- fused aggregate + GEMM ----------
// 64-node tile per block. LDS A-tile [64][512] bf16, XOR-swizzled 16B granules:
// granule g at (row m, col c) stored at g0=(c>>3) -> g = g0 ^ (m&7).
// Phases: ph0 = rels 0-3 (K 0..511), ph1 = rels 4-7 (K 512..1023), self (K 1024..1151).
__global__ __launch_bounds__(256, 2) void fused_kernel(
        const unsigned short* __restrict__ xb,
        const int* __restrict__ offsets,      // nb+1, sentinel = E
        const int* __restrict__ sorted_src,
        const unsigned short* __restrict__ Bt,
        const float* __restrict__ bias,
        float* __restrict__ out,
        int Nn) {
    __shared__ unsigned short As[BLK_M * PHK];   // 65536 B exactly

    const int tid  = threadIdx.x;
    const int lane = tid & 63;
    const int w    = tid >> 6;
    const int wm   = w & 1;        // 2 m-slots of 32 rows
    const int wn   = w >> 1;       // 2 n-slots of 64 cols
    const int l16  = lane & 15;
    const int q    = lane >> 4;
    const int row0 = blockIdx.x * BLK_M;

    float4v acc[2][4] = {};

    // ---------------- rel phases ----------------
    for (int ph = 0; ph < 2; ++ph) {
        // ---- gather: wave w owns local nodes w*16..w*16+15; 2 nodes/group ----
        for (int g2 = 0; g2 < 8; ++g2) {
            int ln0 = w * 16 + g2 * 2;
            float axv[8], ayv[8];
            int base[8], cnt[8];
            int mx = 0;
            float inv[2];
#pragma unroll
            for (int nn = 0; nn < 2; ++nn) {
                int node = row0 + ln0 + nn;
                if (node < Nn) {
                    int d0 = offsets[node * RNUM];
                    int d1 = offsets[node * RNUM + RNUM];
                    inv[nn] = 1.0f / fmaxf((float)(d1 - d0), 1.0f);
                } else inv[nn] = 0.0f;
            }
#pragma unroll
            for (int c = 0; c < 8; ++c) {
                axv[c] = 0.f; ayv[c] = 0.f;
                int node = row0 + ln0 + (c >> 2);
                int s = 0, e2 = 0;
                if (node < Nn) {
                    int b = node * RNUM + ph * 4 + (c & 3);
                    s = offsets[b]; e2 = offsets[b + 1];
                }
                base[c] = s; cnt[c] = e2 - s;
                mx = max(mx, cnt[c]);
            }
            int src[8];
#pragma unroll
            for (int c = 0; c < 8; ++c)
                src[c] = (cnt[c] > 0) ? sorted_src[base[c]] : 0;
            for (int j = 0; j < mx; ++j) {
                unsigned int u[8];
#pragma unroll
                for (int c = 0; c < 8; ++c)
                    if (j < cnt[c])
                        u[c] = *(const unsigned int*)(xb + (size_t)src[c] * D + lane * 2);
#pragma unroll
                for (int c = 0; c < 8; ++c)
                    if (j + 1 < cnt[c])
                        src[c] = sorted_src[base[c] + j + 1];
#pragma unroll
                for (int c = 0; c < 8; ++c)
                    if (j < cnt[c]) {
                        axv[c] += b2f_lo(u[c]);
                        ayv[c] += b2f_hi(u[c]);
                    }
            }
            // scale + swizzled LDS write (dword per lane, 2-way banks = free)
#pragma unroll
            for (int c = 0; c < 8; ++c) {
                int m  = ln0 + (c >> 2);
                int rl = c & 3;
                float iv = inv[c >> 2];
                unsigned int pk = f2b(axv[c] * iv) | (f2b(ayv[c] * iv) << 16);
                int g0 = rl * 16 + (lane >> 2);
                int g  = g0 ^ (m & 7);
                *(unsigned int*)((char*)As + m * 1024 + g * 16 + (lane & 3) * 4) = pk;
            }
        }
        __syncthreads();

        // ---- MFMA over this phase's 512 K-columns; B-frags from global ----
        const unsigned short* Bph = Bt + ph * PHK;
#pragma unroll 4
        for (int kk = 0; kk < PHK; kk += 32) {
            short8 a[2], b[4];
#pragma unroll
            for (int mi = 0; mi < 2; ++mi) {
                int m = wm * 32 + mi * 16 + l16;
                int g = ((kk >> 3) + q) ^ (m & 7);
                a[mi] = *reinterpret_cast<const short8*>((char*)As + m * 1024 + g * 16);
            }
#pragma unroll
            for (int ni = 0; ni < 4; ++ni)
                b[ni] = *reinterpret_cast<const short8*>(
                    Bph + (size_t)(wn * 64 + ni * 16 + l16) * KTOT + kk + q * 8);
#pragma unroll
            for (int mi = 0; mi < 2; ++mi)
#pragma unroll
                for (int ni = 0; ni < 4; ++ni)
                    acc[mi][ni] = __builtin_amdgcn_mfma_f32_16x16x32_bf16(
                        a[mi], b[ni], acc[mi][ni], 0, 0, 0);
        }
        __syncthreads();   // before next phase overwrites As
    }

    // ---------------- self phase (K 1024..1151) ----------------
    // copy xb tile rows into As cols 0..127 (swizzled), 16B per thread x4
#pragma unroll
    for (int i = 0; i < 4; ++i) {
        int G  = i * 256 + tid;          // 1024 granules = 64 rows x 16
        int m  = G >> 4;
        int g0 = G & 15;
        int g  = g0 ^ (m & 7);
        uint4 v = make_uint4(0, 0, 0, 0);
        if (row0 + m < Nn)
            v = *(const uint4*)(xb + (size_t)(row0 + m) * D + g0 * 8);
        *(uint4*)((char*)As + m * 1024 + g * 16) = v;
    }
    __syncthreads();
    {
        const unsigned short* Bph = Bt + KREL;
#pragma unroll
        for (int kk = 0; kk < D; kk += 32) {
            short8 a[2], b[4];
#pragma unroll
            for (int mi = 0; mi < 2; ++mi) {
                int m = wm * 32 + mi * 16 + l16;
                int g = ((kk >> 3) + q) ^ (m & 7);
                a[mi] = *reinterpret_cast<const short8*>((char*)As + m * 1024 + g * 16);
            }
#pragma unroll
            for (int ni = 0; ni < 4; ++ni)
                b[ni] = *reinterpret_cast<const short8*>(
                    Bph + (size_t)(wn * 64 + ni * 16 + l16) * KTOT + kk + q * 8);
#pragma unroll
            for (int mi = 0; mi < 2; ++mi)
#pragma unroll
                for (int ni = 0; ni < 4; ++ni)
                    acc[mi][ni] = __builtin_amdgcn_mfma_f32_16x16x32_bf16(
                        a[mi], b[ni], acc[mi][ni], 0, 0, 0);
        }
    }

    // ---------------- epilogue: + bias, relu, store fp32 ----------------
#pragma unroll
    for (int ni = 0; ni < 4; ++ni) {
        int c = wn * 64 + ni * 16 + l16;
        float bv = bias[c];
#pragma unroll
        for (int mi = 0; mi < 2; ++mi) {
#pragma unroll
            for (int j = 0; j < 4; ++j) {
                int gr = row0 + wm * 32 + mi * 16 + q * 4 + j;
                if (gr < Nn)
                    out[(size_t)gr * D + c] = fmaxf(acc[mi][ni][j] + bv, 0.0f);
            }
        }
    }
}

extern "C" void kernel_launch(void* const* d_in, const int* in_sizes, int n_in,
                              void* d_out, int out_size, void* d_ws, size_t ws_size,
                              hipStream_t stream) {
    const float* x      = (const float*)d_in[0];
    const float* W_rel  = (const float*)d_in[1];
    const float* W_self = (const float*)d_in[2];
    const float* W_bias = (const float*)d_in[3];
    const int*   ei     = (const int*)d_in[4];
    const int*   et     = (const int*)d_in[5];

    const int Nn = in_sizes[0] / D;       // 50000
    const int E  = in_sizes[4] / 2;       // 800000
    const int nb = Nn * RNUM;             // 400000 bins
    const int nparts = (nb + 1023) / 1024;
    const int nblocks = (Nn + BLK_M - 1) / BLK_M;   // 782

    // ---- workspace layout (256B aligned chunks) ----
    char* p = (char*)d_ws;
    auto take = [&](size_t bytes) { char* q = p; p += (bytes + 255) & ~(size_t)255; return q; };
    unsigned short* xb = (unsigned short*)take((size_t)Nn * D * sizeof(unsigned short));
    unsigned short* Bt = (unsigned short*)take((size_t)128 * KTOT * sizeof(unsigned short));
    int* hist    = (int*)take((size_t)nb * sizeof(int));
    int* offsets = (int*)take((size_t)(nb + 1) * sizeof(int));
    int* cursor  = (int*)take((size_t)nb * sizeof(int));
    int* bsum    = (int*)take(1024 * sizeof(int));
    int* sorted  = (int*)take((size_t)E * sizeof(int));

    hipMemsetAsync(hist, 0, (size_t)nb * sizeof(int), stream);

    const int xb_blocks = (Nn * 32 + 255) / 256;
    const int bt_blocks = (128 * KTOT + 255) / 256;
    prep_kernel<<<xb_blocks + bt_blocks, 256, 0, stream>>>(x, W_rel, W_self, xb, Bt, Nn, xb_blocks);
    hist_kernel<<<(E + 255) / 256, 256, 0, stream>>>(ei, et, hist, E);
    scan1_kernel<<<nparts, 256, 0, stream>>>(hist, bsum, nb);
    scan2_kernel<<<1, 1024, 0, stream>>>(bsum, nparts);
    scan3_kernel<<<nparts, 256, 0, stream>>>(hist, bsum, offsets, cursor, nb, E);
    reorder_kernel<<<(E + 255) / 256, 256, 0, stream>>>(ei, et, cursor, sorted, E);
    fused_kernel<<<nblocks, 256, 0, stream>>>(xb, offsets, sorted, Bt, W_bias, (float*)d_out, Nn);
}

// Round 5
// 302.780 us; speedup vs baseline: 1.5707x; 1.5707x over previous
//
#include <hip/hip_runtime.h>
#include <hip/hip_bf16.h>

// RGCN layer: out = relu(x @ W_self^T + b + agg/deg)
// Pipeline (atomic-free, split kernels — R4 fusion reverted: 64KB-LDS fusion
// dropped occupancy to 2 blocks/CU and serialized gather vs MFMA):
//   0. prep: xb = bf16(x), A[:,1024:1152] = bf16(x), Bt = bf16([W_rel; W_self^T])
//   1. counting-sort edges by key = dst*8+rel (hist -> scan -> reorder src)
//   2. aggregate: ONE WAVE PER NODE (edges contiguous after sort):
//      coalesced 64-index src load + shfl broadcast, 8 row-gathers in flight,
//      8 per-rel register accumulators (uniform switch), bf16 write to A.
//   3. one K=1152 bf16 MFMA GEMM: out = relu(A @ Bt^T + b)

#define D 128
#define RNUM 8
#define KREL (RNUM * D)      // 1024
#define KTOT (KREL + D)      // 1152
#define BLK_M 64

typedef short short8 __attribute__((ext_vector_type(8)));
typedef float float4v __attribute__((ext_vector_type(4)));

// fp32 -> bf16 round-nearest-even (bit pattern)
static __device__ __forceinline__ unsigned int f2b(float f) {
    unsigned int u = __float_as_uint(f);
    return (u + 0x7fffu + ((u >> 16) & 1u)) >> 16;
}
static __device__ __forceinline__ float b2f_lo(unsigned int u) {
    return __uint_as_float(u << 16);
}
static __device__ __forceinline__ float b2f_hi(unsigned int u) {
    return __uint_as_float(u & 0xffff0000u);
}

static __device__ __forceinline__ void gl_lds16(const void* g, void* l) {
    __builtin_amdgcn_global_load_lds(
        (const __attribute__((address_space(1))) unsigned int*)g,
        (__attribute__((address_space(3))) unsigned int*)l, 16, 0, 0);
}

// ---------- fused prep ----------
// blocks [0, xb_blocks): x -> xb (bf16) and A self columns
// blocks [xb_blocks, ...): Bt build: bf16 [128 out][1152 k]
__global__ void prep_kernel(const float* __restrict__ x,
                            const float* __restrict__ W_rel,
                            const float* __restrict__ W_self,
                            unsigned short* __restrict__ xb,
                            unsigned short* __restrict__ A,
                            unsigned short* __restrict__ Bt,
                            int Nn, int xb_blocks) {
    if (blockIdx.x < (unsigned)xb_blocks) {
        int t = blockIdx.x * 256 + threadIdx.x;
        int n = t >> 5;              // 32 threads/row, 4 cols each
        int c = (t & 31) * 4;
        if (n >= Nn) return;
        float4 v = *(const float4*)(x + (size_t)n * D + c);
        unsigned int p0 = f2b(v.x) | (f2b(v.y) << 16);
        unsigned int p1 = f2b(v.z) | (f2b(v.w) << 16);
        uint2 pk = make_uint2(p0, p1);
        *(uint2*)(xb + (size_t)n * D + c) = pk;
        *(uint2*)(A + (size_t)n * KTOT + KREL + c) = pk;
    } else {
        int idx = (blockIdx.x - xb_blocks) * 256 + threadIdx.x;
        if (idx >= 128 * KTOT) return;
        int o = idx / KTOT;
        int k = idx - o * KTOT;
        float v = (k < KREL) ? W_rel[(size_t)k * D + o]   // [r][d][o] flat = k*128+o
                             : W_self[(size_t)o * D + (k - KREL)];
        Bt[idx] = (unsigned short)f2b(v);
    }
}

// ---------- counting sort ----------
__global__ void hist_kernel(const int* __restrict__ ei, const int* __restrict__ et,
                            int* __restrict__ hist, int E) {
    int e = blockIdx.x * 256 + threadIdx.x;
    if (e >= E) return;
    int key = ei[E + e] * RNUM + et[e];
    atomicAdd(hist + key, 1);
}

__global__ void scan1_kernel(const int* __restrict__ hist, int* __restrict__ bsum, int nb) {
    __shared__ int red[256];
    int t = threadIdx.x;
    int base = blockIdx.x * 1024 + t * 4;
    int s = 0;
#pragma unroll
    for (int i = 0; i < 4; ++i) if (base + i < nb) s += hist[base + i];
    red[t] = s;
    __syncthreads();
    for (int off = 128; off > 0; off >>= 1) {
        if (t < off) red[t] += red[t + off];
        __syncthreads();
    }
    if (t == 0) bsum[blockIdx.x] = red[0];
}

__global__ void scan2_kernel(int* __restrict__ bsum, int nparts) {
    __shared__ int tmp[1024];
    int t = threadIdx.x;
    tmp[t] = (t < nparts) ? bsum[t] : 0;
    __syncthreads();
    for (int off = 1; off < 1024; off <<= 1) {
        int v = (t >= off) ? tmp[t - off] : 0;
        __syncthreads();
        tmp[t] += v;
        __syncthreads();
    }
    if (t < nparts) bsum[t] = (t == 0) ? 0 : tmp[t - 1];   // exclusive
}

__global__ void scan3_kernel(const int* __restrict__ hist, const int* __restrict__ bsum,
                             int* __restrict__ offsets, int* __restrict__ cursor,
                             int nb, int E) {
    __shared__ int red[256];
    int t = threadIdx.x;
    int base = blockIdx.x * 1024 + t * 4;
    int v[4]; int s = 0;
#pragma unroll
    for (int i = 0; i < 4; ++i) { v[i] = (base + i < nb) ? hist[base + i] : 0; s += v[i]; }
    red[t] = s;
    __syncthreads();
    for (int off = 1; off < 256; off <<= 1) {       // Hillis-Steele inclusive
        int u = (t >= off) ? red[t - off] : 0;
        __syncthreads();
        red[t] += u;
        __syncthreads();
    }
    int p = bsum[blockIdx.x] + red[t] - s;          // exclusive prefix for this thread
#pragma unroll
    for (int i = 0; i < 4; ++i) {
        if (base + i < nb) { offsets[base + i] = p; cursor[base + i] = p; }
        p += v[i];
    }
    if (blockIdx.x == 0 && t == 0) offsets[nb] = E;  // sentinel
}

__global__ void reorder_kernel(const int* __restrict__ ei, const int* __restrict__ et,
                               int* __restrict__ cursor, int* __restrict__ sorted_src, int E) {
    int e = blockIdx.x * 256 + threadIdx.x;
    if (e >= E) return;
    int key = ei[E + e] * RNUM + et[e];
    int pos = atomicAdd(cursor + key, 1);
    sorted_src[pos] = ei[e];
}

// ---------- aggregation: one wave per node, 8 gathers in flight ----------
__global__ __launch_bounds__(256) void aggregate_kernel(
        const unsigned short* __restrict__ xb,
        const int* __restrict__ offsets,      // nb+1 entries, sentinel = E
        const int* __restrict__ sorted_src,
        unsigned short* __restrict__ A,
        int Nn) {
    int node = blockIdx.x * 4 + (threadIdx.x >> 6);
    if (node >= Nn) return;
    int lane = threadIdx.x & 63;

    // lanes 0..8 hold offsets[node*8 + lane]; others duplicate the last
    int off_l = offsets[node * RNUM + (lane < RNUM ? lane : RNUM)];
    int b0 = __shfl(off_l, 0);
    int b8 = __shfl(off_l, RNUM);

    float accx[RNUM] = {0.f, 0.f, 0.f, 0.f, 0.f, 0.f, 0.f, 0.f};
    float accy[RNUM] = {0.f, 0.f, 0.f, 0.f, 0.f, 0.f, 0.f, 0.f};

    for (int base = b0; base < b8; base += 64) {
        int nE = b8 - base; if (nE > 64) nE = 64;
        // coalesced load of up to 64 src indices
        int mysrc = sorted_src[base + (lane < nE ? lane : nE - 1)];
        // per-lane rel of edge (base+lane): count boundaries passed
        int myrel = 0;
#pragma unroll
        for (int r = 1; r < RNUM; ++r)
            myrel += (base + lane >= __shfl(off_l, r)) ? 1 : 0;

        for (int j0 = 0; j0 < nE; j0 += 8) {
            int cnt = nE - j0; if (cnt > 8) cnt = 8;
            unsigned int u[8];
#pragma unroll
            for (int j = 0; j < 8; ++j)
                if (j < cnt) {
                    int s = __shfl(mysrc, j0 + j);
                    u[j] = *(const unsigned int*)(xb + (size_t)s * D + lane * 2);
                }
#pragma unroll
            for (int j = 0; j < 8; ++j)
                if (j < cnt) {
                    int r = __builtin_amdgcn_readfirstlane(__shfl(myrel, j0 + j));
                    float lx = b2f_lo(u[j]), ly = b2f_hi(u[j]);
                    switch (r) {
                        case 0: accx[0] += lx; accy[0] += ly; break;
                        case 1: accx[1] += lx; accy[1] += ly; break;
                        case 2: accx[2] += lx; accy[2] += ly; break;
                        case 3: accx[3] += lx; accy[3] += ly; break;
                        case 4: accx[4] += lx; accy[4] += ly; break;
                        case 5: accx[5] += lx; accy[5] += ly; break;
                        case 6: accx[6] += lx; accy[6] += ly; break;
                        default: accx[7] += lx; accy[7] += ly; break;
                    }
                }
        }
    }

    float inv = 1.0f / fmaxf((float)(b8 - b0), 1.0f);
#pragma unroll
    for (int r = 0; r < RNUM; ++r) {
        unsigned int pk = f2b(accx[r] * inv) | (f2b(accy[r] * inv) << 16);
        *(unsigned int*)(A + (size_t)node * KTOT + r * D + lane * 2) = pk;
    }
}

// ---------- GEMM: out[64 x 128 tile] = relu(A @ Bt^T + b) ----------
__global__ __launch_bounds__(256) void gemm_kernel(
        const unsigned short* __restrict__ A,
        const unsigned short* __restrict__ Bt,
        const float* __restrict__ bias,
        float* __restrict__ out,
        int Nn) {
    __shared__ unsigned short As[BLK_M * 32];    // 64 rows x 32 k (no pad: global_load_lds)
    __shared__ unsigned short Bs[128 * 32];

    const int tid  = threadIdx.x;
    const int lane = tid & 63;
    const int w    = tid >> 6;
    const int wm   = w & 1;        // 2 m-slots of 32 rows
    const int wn   = w >> 1;       // 2 n-slots of 64 cols
    const int l16  = lane & 15;
    const int q    = lane >> 4;
    const int row0 = blockIdx.x * BLK_M;

    float4v acc[2][4] = {};

    // staging addresses: lane i -> row chunk (i/4), 16B piece (i%4)
    const int sr = lane >> 2;          // 0..15
    const int sc = (lane & 3) * 8;     // bf16 elems: 0,8,16,24

    for (int kk = 0; kk < KTOT; kk += 32) {
        // A: wave w stages rows w*16 .. w*16+15 (1024B)
        {
            int r = w * 16 + sr;
            const unsigned short* g = A + (size_t)(row0 + r) * KTOT + kk + sc;
            gl_lds16(g, &As[w * 512]);
        }
        // B: wave w stages rows w*32+p*16, p in {0,1}
#pragma unroll
        for (int p = 0; p < 2; ++p) {
            int r = w * 32 + p * 16 + sr;
            const unsigned short* g = Bt + (size_t)r * KTOT + kk + sc;
            gl_lds16(g, &Bs[(w * 2 + p) * 512]);
        }
        __syncthreads();

        short8 a[2], b[4];
#pragma unroll
        for (int mi = 0; mi < 2; ++mi)
            a[mi] = *reinterpret_cast<const short8*>(&As[(wm * 32 + mi * 16 + l16) * 32 + q * 8]);
#pragma unroll
        for (int ni = 0; ni < 4; ++ni)
            b[ni] = *reinterpret_cast<const short8*>(&Bs[(wn * 64 + ni * 16 + l16) * 32 + q * 8]);
#pragma unroll
        for (int mi = 0; mi < 2; ++mi)
#pragma unroll
            for (int ni = 0; ni < 4; ++ni)
                acc[mi][ni] = __builtin_amdgcn_mfma_f32_16x16x32_bf16(a[mi], b[ni], acc[mi][ni], 0, 0, 0);
        __syncthreads();
    }

#pragma unroll
    for (int ni = 0; ni < 4; ++ni) {
        int c = wn * 64 + ni * 16 + l16;
        float bv = bias[c];
#pragma unroll
        for (int mi = 0; mi < 2; ++mi) {
#pragma unroll
            for (int j = 0; j < 4; ++j) {
                int gr = row0 + wm * 32 + mi * 16 + q * 4 + j;
                if (gr < Nn)
                    out[(size_t)gr * D + c] = fmaxf(acc[mi][ni][j] + bv, 0.0f);
            }
        }
    }
}

extern "C" void kernel_launch(void* const* d_in, const int* in_sizes, int n_in,
                              void* d_out, int out_size, void* d_ws, size_t ws_size,
                              hipStream_t stream) {
    const float* x      = (const float*)d_in[0];
    const float* W_rel  = (const float*)d_in[1];
    const float* W_self = (const float*)d_in[2];
    const float* W_bias = (const float*)d_in[3];
    const int*   ei     = (const int*)d_in[4];
    const int*   et     = (const int*)d_in[5];

    const int Nn = in_sizes[0] / D;       // 50000
    const int E  = in_sizes[4] / 2;       // 800000
    const int nb = Nn * RNUM;             // 400000 bins
    const int nparts = (nb + 1023) / 1024;
    const int npad = ((Nn + BLK_M - 1) / BLK_M) * BLK_M;  // pad rows for staging loads

    // ---- workspace layout (256B aligned chunks) ----
    char* p = (char*)d_ws;
    auto take = [&](size_t bytes) { char* q = p; p += (bytes + 255) & ~(size_t)255; return q; };
    unsigned short* A    = (unsigned short*)take((size_t)npad * KTOT * sizeof(unsigned short));
    unsigned short* xb   = (unsigned short*)take((size_t)Nn * D * sizeof(unsigned short));
    unsigned short* Bt   = (unsigned short*)take((size_t)128 * KTOT * sizeof(unsigned short));
    int* hist    = (int*)take((size_t)nb * sizeof(int));
    int* offsets = (int*)take((size_t)(nb + 1) * sizeof(int));
    int* cursor  = (int*)take((size_t)nb * sizeof(int));
    int* bsum    = (int*)take(1024 * sizeof(int));
    int* sorted  = (int*)take((size_t)E * sizeof(int));

    hipMemsetAsync(hist, 0, (size_t)nb * sizeof(int), stream);

    const int xb_blocks = (Nn * 32 + 255) / 256;
    const int bt_blocks = (128 * KTOT + 255) / 256;
    prep_kernel<<<xb_blocks + bt_blocks, 256, 0, stream>>>(x, W_rel, W_self, xb, A, Bt, Nn, xb_blocks);
    hist_kernel<<<(E + 255) / 256, 256, 0, stream>>>(ei, et, hist, E);
    scan1_kernel<<<nparts, 256, 0, stream>>>(hist, bsum, nb);
    scan2_kernel<<<1, 1024, 0, stream>>>(bsum, nparts);
    scan3_kernel<<<nparts, 256, 0, stream>>>(hist, bsum, offsets, cursor, nb, E);
    reorder_kernel<<<(E + 255) / 256, 256, 0, stream>>>(ei, et, cursor, sorted, E);
    aggregate_kernel<<<(Nn + 3) / 4, 256, 0, stream>>>(xb, offsets, sorted, A, Nn);
    gemm_kernel<<<npad / BLK_M, 256, 0, stream>>>(A, Bt, W_bias, (float*)d_out, Nn);
}